// Round 3
// baseline (966.710 us; speedup 1.0000x reference)
//
#include <hip/hip_runtime.h>
#include <hip/hip_fp16.h>

#define EMB 64
#define SCAN_TILE 1024     // elements per scan block (256 thr x 4)

typedef int   iv4 __attribute__((ext_vector_type(4)));
typedef float fv4 __attribute__((ext_vector_type(4)));
typedef unsigned uv2 __attribute__((ext_vector_type(2)));

// ---- per-row histogram via global atomics (counts is L2-resident, 800 KB) ----
__global__ __launch_bounds__(256) void row_hist(const int* __restrict__ rows,
                                                int* __restrict__ counts, int nnz) {
    int stride = gridDim.x * blockDim.x;
    int tid = blockIdx.x * blockDim.x + threadIdx.x;
    int n4 = nnz >> 2;
    for (int q = tid; q < n4; q += stride) {
        iv4 r = __builtin_nontemporal_load((const iv4*)rows + q);
        atomicAdd(&counts[r.x], 1);
        atomicAdd(&counts[r.y], 1);
        atomicAdd(&counts[r.z], 1);
        atomicAdd(&counts[r.w], 1);
    }
    int base = n4 << 2;
    if (tid < (nnz - base)) atomicAdd(&counts[rows[base + tid]], 1);
}

// ---- hierarchical exclusive scan: pass 1 (per-block, 1024 elems) ----
__global__ __launch_bounds__(256) void scan1(const int* __restrict__ counts,
                                             int* __restrict__ offs,
                                             int* __restrict__ btot, int n) {
    __shared__ int lds[256];
    int tid = threadIdx.x;
    int i0 = blockIdx.x * SCAN_TILE + tid * 4;
    int v0 = 0, v1 = 0, v2 = 0, v3 = 0;
    if (i0 + 3 < n) {
        iv4 c = *(const iv4*)(counts + i0);
        v0 = c.x; v1 = c.y; v2 = c.z; v3 = c.w;
    } else {
        if (i0     < n) v0 = counts[i0];
        if (i0 + 1 < n) v1 = counts[i0 + 1];
        if (i0 + 2 < n) v2 = counts[i0 + 2];
        if (i0 + 3 < n) v3 = counts[i0 + 3];
    }
    int tsum = v0 + v1 + v2 + v3;
    int x = tsum;
    lds[tid] = x; __syncthreads();
    for (int off = 1; off < 256; off <<= 1) {
        int t = (tid >= off) ? lds[tid - off] : 0;
        __syncthreads();
        x += t; lds[tid] = x; __syncthreads();
    }
    int ex = x - tsum;                    // exclusive base within block
    if (i0     < n) offs[i0]     = ex;
    if (i0 + 1 < n) offs[i0 + 1] = ex + v0;
    if (i0 + 2 < n) offs[i0 + 2] = ex + v0 + v1;
    if (i0 + 3 < n) offs[i0 + 3] = ex + v0 + v1 + v2;
    if (tid == 255) btot[blockIdx.x] = x; // block total
}

// ---- scan pass 2: exclusive scan of block totals (nb <= 256) ----
__global__ void scan2(int* __restrict__ btot, int nb) {
    __shared__ int lds[256];
    int tid = threadIdx.x;
    int v = (tid < nb) ? btot[tid] : 0;
    int x = v;
    lds[tid] = x; __syncthreads();
    for (int off = 1; off < 256; off <<= 1) {
        int t = (tid >= off) ? lds[tid - off] : 0;
        __syncthreads();
        x += t; lds[tid] = x; __syncthreads();
    }
    if (tid < nb) btot[tid] = x - v;      // exclusive
}

// ---- scan pass 3: add block base, emit offs + cursor ----
__global__ __launch_bounds__(256) void scan3(int* __restrict__ offs,
                                             int* __restrict__ cursor,
                                             const int* __restrict__ btot,
                                             int n, int nnz) {
    int b = btot[blockIdx.x];
    int i0 = blockIdx.x * SCAN_TILE + threadIdx.x * 4;
    if (i0 + 3 < n) {
        iv4 o = *(const iv4*)(offs + i0);
        o.x += b; o.y += b; o.z += b; o.w += b;
        *(iv4*)(offs + i0) = o;
        *(iv4*)(cursor + i0) = o;
    } else {
        for (int j = 0; j < 4; ++j)
            if (i0 + j < n) {
                int t = offs[i0 + j] + b;
                offs[i0 + j] = t;
                cursor[i0 + j] = t;
            }
    }
    if (blockIdx.x == 0 && threadIdx.x == 0) offs[n] = nnz;
}

// ---- direct scatter into exact CSR slots (order within row arbitrary) ----
__global__ __launch_bounds__(256) void direct_scatter(
        const int* __restrict__ rows, const int* __restrict__ cols,
        const float* __restrict__ vals, int* __restrict__ cursor,
        int2* __restrict__ packed, int nnz) {
    int stride = gridDim.x * blockDim.x;
    int tid = blockIdx.x * blockDim.x + threadIdx.x;
    int n4 = nnz >> 2;
    for (int q = tid; q < n4; q += stride) {
        iv4 r = __builtin_nontemporal_load((const iv4*)rows + q);
        iv4 c = __builtin_nontemporal_load((const iv4*)cols + q);
        fv4 v = __builtin_nontemporal_load((const fv4*)vals + q);
        int s0 = atomicAdd(&cursor[r.x], 1);
        int s1 = atomicAdd(&cursor[r.y], 1);
        int s2 = atomicAdd(&cursor[r.z], 1);
        int s3 = atomicAdd(&cursor[r.w], 1);
        packed[s0] = make_int2(c.x, __float_as_int(v.x));
        packed[s1] = make_int2(c.y, __float_as_int(v.y));
        packed[s2] = make_int2(c.z, __float_as_int(v.z));
        packed[s3] = make_int2(c.w, __float_as_int(v.w));
    }
    int base = n4 << 2;
    if (tid < (nnz - base)) {
        int i = base + tid;
        int s = atomicAdd(&cursor[rows[i]], 1);
        packed[s] = make_int2(cols[i], __float_as_int(vals[i]));
    }
}

// ---- cast fp32 user||item embeddings into one concatenated fp16 buffer ----
__global__ __launch_bounds__(256) void cast_concat_half(
        const float* __restrict__ a, const float* __restrict__ b,
        int na4, int ntot4, __half* __restrict__ o) {
    int stride = gridDim.x * blockDim.x;
    for (int i = blockIdx.x * blockDim.x + threadIdx.x; i < ntot4; i += stride) {
        fv4 v = (i < na4) ? ((const fv4*)a)[i] : ((const fv4*)b)[i - na4];
        __half2 h0 = __floats2half2_rn(v.x, v.y);
        __half2 h1 = __floats2half2_rn(v.z, v.w);
        uv2 w;
        w.x = *(unsigned*)&h0;
        w.y = *(unsigned*)&h1;
        *((uv2*)o + i) = w;
    }
}

// ---- SpMM: one wave (64 lanes == EMB) per row; fp16 gather, fp32 accum ----
// mode 0: out = acc;  yh = acc   (layer 0)
// mode 1: out += acc; yh = acc   (layer 1)
// mode 2: out = (out+acc)/3      (layer 2, no y write)
__global__ __launch_bounds__(256) void spmm_row_h(
        const int* __restrict__ offs, const int2* __restrict__ packed,
        const __half* __restrict__ xh,
        __half* __restrict__ yh, float* __restrict__ out, int n_rows, int mode) {
    int wid = (blockIdx.x * blockDim.x + threadIdx.x) >> 6;
    if (wid >= n_rows) return;
    int lane = threadIdx.x & 63;
    int r = __builtin_amdgcn_readfirstlane(wid);   // wave-uniform -> scalar path
    int s = offs[r];
    int e = offs[r + 1];
    const unsigned long long* pk = (const unsigned long long*)packed;
    float a0 = 0.f, a1 = 0.f, a2 = 0.f, a3 = 0.f;
    int k = s;
    for (; k + 3 < e; k += 4) {
        unsigned long long w0 = __builtin_nontemporal_load(pk + k);
        unsigned long long w1 = __builtin_nontemporal_load(pk + k + 1);
        unsigned long long w2 = __builtin_nontemporal_load(pk + k + 2);
        unsigned long long w3 = __builtin_nontemporal_load(pk + k + 3);
        int c0 = (int)(unsigned)w0;
        int c1 = (int)(unsigned)w1;
        int c2 = (int)(unsigned)w2;
        int c3 = (int)(unsigned)w3;
        float h0 = __half2float(xh[(c0 << 6) + lane]);
        float h1 = __half2float(xh[(c1 << 6) + lane]);
        float h2 = __half2float(xh[(c2 << 6) + lane]);
        float h3 = __half2float(xh[(c3 << 6) + lane]);
        a0 += __int_as_float((int)(w0 >> 32)) * h0;
        a1 += __int_as_float((int)(w1 >> 32)) * h1;
        a2 += __int_as_float((int)(w2 >> 32)) * h2;
        a3 += __int_as_float((int)(w3 >> 32)) * h3;
    }
    for (; k < e; ++k) {
        unsigned long long w = __builtin_nontemporal_load(pk + k);
        a0 += __int_as_float((int)(w >> 32)) *
              __half2float(xh[(((int)(unsigned)w) << 6) + lane]);
    }
    float acc = (a0 + a1) + (a2 + a3);
    size_t oi = ((size_t)r << 6) + lane;
    if (mode == 0) {
        __builtin_nontemporal_store(acc, &out[oi]);
        yh[oi] = __float2half_rn(acc);
    } else if (mode == 1) {
        float o = __builtin_nontemporal_load(&out[oi]);
        __builtin_nontemporal_store(o + acc, &out[oi]);
        yh[oi] = __float2half_rn(acc);
    } else {
        float o = __builtin_nontemporal_load(&out[oi]);
        __builtin_nontemporal_store((o + acc) * (1.0f / 3.0f), &out[oi]);
    }
}

extern "C" void kernel_launch(void* const* d_in, const int* in_sizes, int n_in,
                              void* d_out, int out_size, void* d_ws, size_t ws_size,
                              hipStream_t stream) {
    const float* user_emb = (const float*)d_in[0];
    const float* item_emb = (const float*)d_in[1];
    const int*   adj_row  = (const int*)d_in[2];
    const int*   adj_col  = (const int*)d_in[3];
    const float* adj_val  = (const float*)d_in[4];
    float* out = (float*)d_out;

    const int n_user = in_sizes[0] / EMB;
    const int n_item = in_sizes[1] / EMB;
    const int n      = n_user + n_item;
    const int nnz    = in_sizes[2];
    const size_t half_bytes = (size_t)n * EMB * sizeof(__half);
    const int nsb = (n + SCAN_TILE - 1) / SCAN_TILE;   // scan blocks (<=256)

    char* p = (char*)d_ws;
    __half* X0    = (__half*)p; p += half_bytes;
    __half* Ah    = (__half*)p; p += half_bytes;
    __half* Bh    = (__half*)p; p += half_bytes;
    int2*  packed = (int2*)p;  p += (size_t)nnz * sizeof(int2);
    int*   offs   = (int*)p;   p += (size_t)(n + 1) * sizeof(int);
    int*   cursor = (int*)p;   p += (size_t)n * sizeof(int);
    int*   counts = (int*)p;   p += (size_t)n * sizeof(int);
    int*   btot   = (int*)p;   p += (size_t)nsb * sizeof(int);

    // ---- fp16 cast of the layer-0 input (single concat buffer) ----
    cast_concat_half<<<2048, 256, 0, stream>>>(user_emb, item_emb,
                                               n_user * EMB / 4, n * EMB / 4, X0);

    // ---- exact CSR: per-row hist -> scan -> direct scatter ----
    hipMemsetAsync(counts, 0, (size_t)n * sizeof(int), stream);
    row_hist<<<2048, 256, 0, stream>>>(adj_row, counts, nnz);
    scan1<<<nsb, 256, 0, stream>>>(counts, offs, btot, n);
    scan2<<<1, 256, 0, stream>>>(btot, nsb);
    scan3<<<nsb, 256, 0, stream>>>(offs, cursor, btot, n, nnz);
    direct_scatter<<<2048, 256, 0, stream>>>(adj_row, adj_col, adj_val,
                                             cursor, packed, nnz);

    // ---- 3 propagation layers, fused accumulate ----
    const int sgrid = (n * EMB + 255) / 256;   // one wave per row
    spmm_row_h<<<sgrid, 256, 0, stream>>>(offs, packed, X0, Ah, out, n, 0);
    spmm_row_h<<<sgrid, 256, 0, stream>>>(offs, packed, Ah, Bh, out, n, 1);
    spmm_row_h<<<sgrid, 256, 0, stream>>>(offs, packed, Bh, Bh, out, n, 2);
}